// Round 3
// baseline (188.506 us; speedup 1.0000x reference)
//
#include <hip/hip_runtime.h>
#include <math.h>

// SSIM loss, fp32, B=16 C=3 H=W=512, 11x11 Gaussian (sigma=1.5), zero pad.
// R3: conflict-free LDS layout + read2/write2-friendly strides.
//  hbA[42][129]: X,Y horizontal sums   (129 mod 32 == 1 -> bank = r+j, free)
//  hbB[42][193]: XX,YY,XY horizontal sums (193 mod 32 == 1)
//  vertical pass: 1 col x 8 rows/thread, register accumulators
//  interior-block fast path without bounds checks

#define IMG_W 512
#define IMG_H 512
#define PLANES 48
#define TX 64
#define TY 32
#define RAD 5
#define KW 11
#define LY (TY + 2 * RAD)      // 42
#define SA (2 * TX + 1)        // 129 floats per hbA row
#define SB (3 * TX + 1)        // 193 floats per hbB row
#define NT 256
#define GDX (IMG_W / TX)       // 8
#define GDY (IMG_H / TY)       // 16
#define NBLK (GDX * GDY * PLANES)  // 6144

template<bool INTERIOR>
__device__ __forceinline__ void hpass_item(
    int r, int g, int ty0, int bx0,
    const float* __restrict__ xp, const float* __restrict__ yp,
    float* __restrict__ hbA, float* __restrict__ hbB,
    const float* __restrict__ w)
{
    const int gy = ty0 + r;
    const int j0 = bx0 + g * 8;

    float av[24], bv[24];
    const bool rowok = INTERIOR || ((unsigned)gy < (unsigned)IMG_H);
    if (rowok) {
        const float* rowx = xp + (size_t)gy * IMG_W;
        const float* rowy = yp + (size_t)gy * IMG_W;
        #pragma unroll
        for (int v = 0; v < 6; ++v) {
            const int gx = j0 - 8 + 4 * v;   // multiple of 4 -> never straddles
            float4 xa, ya;
            if (INTERIOR || ((unsigned)gx < (unsigned)IMG_W)) {
                xa = *(const float4*)(rowx + gx);
                ya = *(const float4*)(rowy + gx);
            } else {
                xa = make_float4(0.f, 0.f, 0.f, 0.f);
                ya = make_float4(0.f, 0.f, 0.f, 0.f);
            }
            av[4*v+0] = xa.x; av[4*v+1] = xa.y; av[4*v+2] = xa.z; av[4*v+3] = xa.w;
            bv[4*v+0] = ya.x; bv[4*v+1] = ya.y; bv[4*v+2] = ya.z; bv[4*v+3] = ya.w;
        }
    } else {
        #pragma unroll
        for (int i = 0; i < 24; ++i) { av[i] = 0.f; bv[i] = 0.f; }
    }

    // Products once per input column (cols j0-5 .. j0+12).
    float AA[18], BB[18], AB[18];
    #pragma unroll
    for (int i = 0; i < 18; ++i) {
        const float A = av[i + 3], B = bv[i + 3];
        AA[i] = A * A; BB[i] = B * B; AB[i] = A * B;
    }

    #pragma unroll
    for (int u = 0; u < 8; ++u) {
        float sxv = 0.f, syv = 0.f, sxx = 0.f, syy = 0.f, sxy = 0.f;
        #pragma unroll
        for (int k = 0; k < KW; ++k) {
            const float wk = w[k];
            sxv += wk * av[u + 3 + k];
            syv += wk * bv[u + 3 + k];
            sxx += wk * AA[u + k];
            syy += wk * BB[u + k];
            sxy += wk * AB[u + k];
        }
        const int c = g * 8 + u;
        hbA[r * SA + c]          = sxv;
        hbA[r * SA + TX + c]     = syv;
        hbB[r * SB + c]          = sxx;
        hbB[r * SB + TX + c]     = syy;
        hbB[r * SB + 2 * TX + c] = sxy;
    }
}

__global__ __launch_bounds__(NT, 3) void ssim_tile_kernel(
    const float* __restrict__ x, const float* __restrict__ y,
    float* __restrict__ partials)
{
    __shared__ float hbA[LY * SA];      // 5418 floats
    __shared__ float hbB[LY * SB];      // 8106 floats  (total 54096B + 16 -> 54272)
    __shared__ float wave_sums[NT / 64];

    float w[KW];
    {
        float s = 0.f;
        #pragma unroll
        for (int k = 0; k < KW; ++k) {
            const float d = (float)(k - RAD);
            w[k] = expf(-d * d * (1.f / (2.f * 1.5f * 1.5f)));
            s += w[k];
        }
        const float inv = 1.f / s;
        #pragma unroll
        for (int k = 0; k < KW; ++k) w[k] *= inv;
    }

    const int tid = threadIdx.x;
    const int plane = blockIdx.z;
    const float* __restrict__ xp = x + (size_t)plane * IMG_H * IMG_W;
    const float* __restrict__ yp = y + (size_t)plane * IMG_H * IMG_W;
    const int bx0 = blockIdx.x * TX;
    const int ty0 = blockIdx.y * TY - RAD;

    // Interior test: all 6 float4 chunks and all 42 rows in-bounds.
    const bool interior =
        (bx0 >= 8) && (bx0 + TX + 8 + 12 <= IMG_W) &&
        (ty0 >= 0) && (ty0 + LY <= IMG_H);

    // ---- Horizontal pass: 336 items = 42 rows x 8 col-groups ----
    if (interior) {
        hpass_item<true>(tid >> 3, tid & 7, ty0, bx0, xp, yp, hbA, hbB, w);
        if (tid < LY * 8 - NT)
            hpass_item<true>(32 + (tid >> 3), tid & 7, ty0, bx0, xp, yp, hbA, hbB, w);
    } else {
        hpass_item<false>(tid >> 3, tid & 7, ty0, bx0, xp, yp, hbA, hbB, w);
        if (tid < LY * 8 - NT)
            hpass_item<false>(32 + (tid >> 3), tid & 7, ty0, bx0, xp, yp, hbA, hbB, w);
    }
    __syncthreads();

    // ---- Vertical pass: 1 column x 8 output rows per thread ----
    const int j  = tid & 63;
    const int i0 = (tid >> 6) * 8;

    float aX[8], aY[8], aXX[8], aYY[8], aXY[8];
    #pragma unroll
    for (int u = 0; u < 8; ++u) {
        aX[u] = 0.f; aY[u] = 0.f; aXX[u] = 0.f; aYY[u] = 0.f; aXY[u] = 0.f;
    }

    #pragma unroll
    for (int rr = 0; rr < 18; ++rr) {
        const int r = i0 + rr;
        const float hX  = hbA[r * SA + j];
        const float hY  = hbA[r * SA + TX + j];
        const float hXX = hbB[r * SB + j];
        const float hYY = hbB[r * SB + TX + j];
        const float hXY = hbB[r * SB + 2 * TX + j];
        const int ulo = (rr - 10) > 0 ? (rr - 10) : 0;
        const int uhi = rr < 7 ? rr : 7;
        #pragma unroll
        for (int u = ulo; u <= uhi; ++u) {
            const float wk = w[rr - u];
            aX[u]  += wk * hX;
            aY[u]  += wk * hY;
            aXX[u] += wk * hXX;
            aYY[u] += wk * hYY;
            aXY[u] += wk * hXY;
        }
    }

    // ---- SSIM map + local sum ----
    float local = 0.f;
    #pragma unroll
    for (int u = 0; u < 8; ++u) {
        const float mx = aX[u], my = aY[u];
        const float mx2 = mx * mx, my2 = my * my, mxy = mx * my;
        const float sx2 = aXX[u] - mx2, sy2 = aYY[u] - my2, sxy = aXY[u] - mxy;
        const float c1 = 1e-4f, c2 = 9e-4f;
        const float num = (2.f * mxy + c1) * (2.f * sxy + c2);
        const float den = (mx2 + my2 + c1) * (sx2 + sy2 + c2) + 1e-8f;
        local += num * __builtin_amdgcn_rcpf(den);
    }

    // ---- Block reduction -> one partial per block ----
    #pragma unroll
    for (int off = 32; off > 0; off >>= 1)
        local += __shfl_down(local, off, 64);
    const int lane = tid & 63, wv = tid >> 6;
    if (lane == 0) wave_sums[wv] = local;
    __syncthreads();
    if (tid == 0) {
        const float s = wave_sums[0] + wave_sums[1] + wave_sums[2] + wave_sums[3];
        const int bid = blockIdx.x + GDX * (blockIdx.y + GDY * blockIdx.z);
        partials[bid] = s;
    }
}

__global__ __launch_bounds__(NT) void ssim_finalize_kernel(
    const float* __restrict__ partials, float* __restrict__ out)
{
    const int tid = threadIdx.x;
    double s = 0.0;
    #pragma unroll 4
    for (int i = tid; i < NBLK; i += NT) s += (double)partials[i];
    #pragma unroll
    for (int off = 32; off > 0; off >>= 1)
        s += __shfl_down(s, off, 64);
    __shared__ double ws_[NT / 64];
    const int lane = tid & 63, wv = tid >> 6;
    if (lane == 0) ws_[wv] = s;
    __syncthreads();
    if (tid == 0) {
        const double t = ws_[0] + ws_[1] + ws_[2] + ws_[3];
        const double n = (double)PLANES * IMG_H * IMG_W;
        out[0] = (float)(1.0 - t / n);
    }
}

extern "C" void kernel_launch(void* const* d_in, const int* in_sizes, int n_in,
                              void* d_out, int out_size, void* d_ws, size_t ws_size,
                              hipStream_t stream)
{
    const float* x = (const float*)d_in[0];
    const float* y = (const float*)d_in[1];
    float* out = (float*)d_out;
    float* partials = (float*)d_ws;   // NBLK floats, fully overwritten each call

    dim3 grid(GDX, GDY, PLANES);
    ssim_tile_kernel<<<grid, NT, 0, stream>>>(x, y, partials);
    ssim_finalize_kernel<<<1, NT, 0, stream>>>(partials, out);
}

// Round 4
// 171.966 us; speedup vs baseline: 1.0962x; 1.0962x over previous
//
#include <hip/hip_runtime.h>
#include <math.h>

// SSIM loss, fp32, B=16 C=3 H=W=512, 11x11 Gaussian (sigma=1.5), zero pad.
// R4: f16 row-pair-packed LDS + v_dot2_f32_f16 vertical conv.
//  - hbh[5][21][65][2]: plane p, row-pair pp, col j, rows (2pp,2pp+1) as f16.
//    row-pair stride 65 dwords (==1 mod 32): conflict-free reads, merge-safe.
//  - horizontal: f32 math from global (float4), item = row-pair x 4 cols,
//    results written as ds_write_b16 (2 halves/dword = 2-way = free).
//  - vertical: 45 b32 reads + 240 dot2 per thread (2 taps/instr).
//  - f16 vertical weights compensated by f32 correction cv = 1/sum(w_f16).

#define IMG_W 512
#define IMG_H 512
#define PLANES 48
#define TX 64
#define TY 32
#define RAD 5
#define KW 11
#define NPAIR 21               // (TY + 2*RAD) / 2 row-pairs
#define SJ 65                  // col stride in dwords (odd -> conflict-free)
#define NT 256
#define GDX (IMG_W / TX)       // 8
#define GDY (IMG_H / TY)       // 16
#define NBLK (GDX * GDY * PLANES)  // 6144

typedef _Float16 h2 __attribute__((ext_vector_type(2)));

#if __has_builtin(__builtin_amdgcn_fdot2)
__device__ __forceinline__ float DOT2(h2 a, h2 b, float c) {
    return __builtin_amdgcn_fdot2(a, b, c, false);
}
#else
__device__ __forceinline__ float DOT2(h2 a, h2 b, float c) {
    return c + (float)a.x * (float)b.x + (float)a.y * (float)b.y;
}
#endif

// One horizontal item: row-pair pp, 4-col group g4. Computes 2 rows x 4 cols
// of the 5 blurred planes and writes f16 halves into the packed LDS layout.
template<bool INTERIOR>
__device__ __forceinline__ void hpass_item(
    int pp, int g4, int ty0, int bx0,
    const float* __restrict__ xp, const float* __restrict__ yp,
    _Float16* __restrict__ hbh,          // [5][NPAIR][SJ][2]
    const float* __restrict__ w)
{
    const int j0 = bx0 + g4 * 4;        // global col of first output

    #pragma unroll
    for (int rr = 0; rr < 2; ++rr) {
        const int gy = ty0 + 2 * pp + rr;
        float av[20], bv[20];
        const bool rowok = INTERIOR || ((unsigned)gy < (unsigned)IMG_H);
        if (rowok) {
            const float* rowx = xp + (size_t)gy * IMG_W;
            const float* rowy = yp + (size_t)gy * IMG_W;
            #pragma unroll
            for (int v = 0; v < 5; ++v) {
                const int gx = j0 - 8 + 4 * v;   // multiple of 4: no straddle
                float4 xa, ya;
                if (INTERIOR || ((unsigned)gx < (unsigned)IMG_W)) {
                    xa = *(const float4*)(rowx + gx);
                    ya = *(const float4*)(rowy + gx);
                } else {
                    xa = make_float4(0.f, 0.f, 0.f, 0.f);
                    ya = make_float4(0.f, 0.f, 0.f, 0.f);
                }
                av[4*v+0] = xa.x; av[4*v+1] = xa.y; av[4*v+2] = xa.z; av[4*v+3] = xa.w;
                bv[4*v+0] = ya.x; bv[4*v+1] = ya.y; bv[4*v+2] = ya.z; bv[4*v+3] = ya.w;
            }
        } else {
            #pragma unroll
            for (int i = 0; i < 20; ++i) { av[i] = 0.f; bv[i] = 0.f; }
        }

        // Products once per used input col (j0-5 .. j0+8 -> av[3..16]).
        float AA[14], BB[14], AB[14];
        #pragma unroll
        for (int i = 0; i < 14; ++i) {
            const float A = av[i + 3], B = bv[i + 3];
            AA[i] = A * A; BB[i] = B * B; AB[i] = A * B;
        }

        #pragma unroll
        for (int cc = 0; cc < 4; ++cc) {
            float sxv = 0.f, syv = 0.f, sxx = 0.f, syy = 0.f, sxy = 0.f;
            #pragma unroll
            for (int k = 0; k < KW; ++k) {
                const float wk = w[k];
                sxv += wk * av[cc + 3 + k];
                syv += wk * bv[cc + 3 + k];
                sxx += wk * AA[cc + k];
                syy += wk * BB[cc + k];
                sxy += wk * AB[cc + k];
            }
            const int c = g4 * 4 + cc;
            const int base = (pp * SJ + c) * 2 + rr;
            const int pstr = NPAIR * SJ * 2;
            hbh[0 * pstr + base] = (_Float16)sxv;
            hbh[1 * pstr + base] = (_Float16)syv;
            hbh[2 * pstr + base] = (_Float16)sxx;
            hbh[3 * pstr + base] = (_Float16)syy;
            hbh[4 * pstr + base] = (_Float16)sxy;
        }
    }
}

__global__ __launch_bounds__(NT, 4) void ssim_tile_kernel(
    const float* __restrict__ x, const float* __restrict__ y,
    float* __restrict__ partials)
{
    __shared__ _Float16 hbh[5 * NPAIR * SJ * 2];   // 27300 B
    __shared__ float wave_sums[NT / 64];

    // Normalized f32 weights; f16 copies for the vertical dot2 path.
    float w[KW];
    {
        float s = 0.f;
        #pragma unroll
        for (int k = 0; k < KW; ++k) {
            const float d = (float)(k - RAD);
            w[k] = expf(-d * d * (1.f / (2.f * 1.5f * 1.5f)));
            s += w[k];
        }
        const float inv = 1.f / s;
        #pragma unroll
        for (int k = 0; k < KW; ++k) w[k] *= inv;
    }
    _Float16 wh[KW];
    float cv;
    {
        float s2 = 0.f;
        #pragma unroll
        for (int k = 0; k < KW; ++k) { wh[k] = (_Float16)w[k]; s2 += (float)wh[k]; }
        cv = 1.f / s2;   // correction for f16 weight quantization
    }
    // Pair-weight tables: w2[parity of output row][pair offset q].
    h2 w2[2][6];
    #pragma unroll
    for (int q = 0; q < 5; ++q) { w2[0][q].x = wh[2*q];   w2[0][q].y = wh[2*q+1]; }
    w2[0][5].x = wh[10]; w2[0][5].y = (_Float16)0.f;
    w2[1][0].x = (_Float16)0.f; w2[1][0].y = wh[0];
    #pragma unroll
    for (int q = 1; q < 6; ++q) { w2[1][q].x = wh[2*q-1]; w2[1][q].y = wh[2*q]; }

    const int tid = threadIdx.x;
    const int plane = blockIdx.z;
    const float* __restrict__ xp = x + (size_t)plane * IMG_H * IMG_W;
    const float* __restrict__ yp = y + (size_t)plane * IMG_H * IMG_W;
    const int bx0 = blockIdx.x * TX;
    const int ty0 = blockIdx.y * TY - RAD;

    const bool interior =
        (bx0 >= 8) && (bx0 + TX - 4 + 12 <= IMG_W) &&
        (ty0 >= 0) && (ty0 + 2 * NPAIR <= IMG_H);

    // ---- Horizontal pass: 336 items = 21 row-pairs x 16 col-quads ----
    if (interior) {
        hpass_item<true>(tid >> 4, tid & 15, ty0, bx0, xp, yp, hbh, w);
        if (tid < NPAIR * 16 - NT)
            hpass_item<true>(16 + (tid >> 4), tid & 15, ty0, bx0, xp, yp, hbh, w);
    } else {
        hpass_item<false>(tid >> 4, tid & 15, ty0, bx0, xp, yp, hbh, w);
        if (tid < NPAIR * 16 - NT)
            hpass_item<false>(16 + (tid >> 4), tid & 15, ty0, bx0, xp, yp, hbh, w);
    }
    __syncthreads();

    // ---- Vertical pass: 1 col x 8 output rows per thread, dot2 taps ----
    const int j  = tid & 63;
    const int P0 = (tid >> 6) * 4;      // first row-pair of this chunk

    float acc[5][8];
    #pragma unroll
    for (int p = 0; p < 5; ++p)
        #pragma unroll
        for (int u = 0; u < 8; ++u) acc[p][u] = 0.f;

    const h2* __restrict__ hb2 = (const h2*)hbh;   // [5][NPAIR][SJ]
    #pragma unroll
    for (int pp = 0; pp < 9; ++pp) {
        h2 v[5];
        #pragma unroll
        for (int p = 0; p < 5; ++p)
            v[p] = hb2[(p * NPAIR + P0 + pp) * SJ + j];
        const int ulo = (2 * pp - 10) > 0 ? (2 * pp - 10) : 0;
        const int uhi = (2 * pp + 1) < 7 ? (2 * pp + 1) : 7;
        #pragma unroll
        for (int u = ulo; u <= uhi; ++u) {
            const h2 wv = w2[u & 1][pp - (u >> 1)];
            #pragma unroll
            for (int p = 0; p < 5; ++p)
                acc[p][u] = DOT2(v[p], wv, acc[p][u]);
        }
    }

    // ---- SSIM map + local sum ----
    float local = 0.f;
    #pragma unroll
    for (int u = 0; u < 8; ++u) {
        const float mx = acc[0][u] * cv, my = acc[1][u] * cv;
        const float xx = acc[2][u] * cv, yy = acc[3][u] * cv, xy = acc[4][u] * cv;
        const float mx2 = mx * mx, my2 = my * my, mxy = mx * my;
        const float sx2 = xx - mx2, sy2 = yy - my2, sxy = xy - mxy;
        const float c1 = 1e-4f, c2 = 9e-4f;
        const float num = (2.f * mxy + c1) * (2.f * sxy + c2);
        const float den = (mx2 + my2 + c1) * (sx2 + sy2 + c2) + 1e-8f;
        local += num * __builtin_amdgcn_rcpf(den);
    }

    // ---- Block reduction -> one partial per block ----
    #pragma unroll
    for (int off = 32; off > 0; off >>= 1)
        local += __shfl_down(local, off, 64);
    const int lane = tid & 63, wv = tid >> 6;
    if (lane == 0) wave_sums[wv] = local;
    __syncthreads();
    if (tid == 0) {
        const float s = wave_sums[0] + wave_sums[1] + wave_sums[2] + wave_sums[3];
        const int bid = blockIdx.x + GDX * (blockIdx.y + GDY * blockIdx.z);
        partials[bid] = s;
    }
}

__global__ __launch_bounds__(NT) void ssim_finalize_kernel(
    const float* __restrict__ partials, float* __restrict__ out)
{
    const int tid = threadIdx.x;
    double s = 0.0;
    #pragma unroll 4
    for (int i = tid; i < NBLK; i += NT) s += (double)partials[i];
    #pragma unroll
    for (int off = 32; off > 0; off >>= 1)
        s += __shfl_down(s, off, 64);
    __shared__ double ws_[NT / 64];
    const int lane = tid & 63, wv = tid >> 6;
    if (lane == 0) ws_[wv] = s;
    __syncthreads();
    if (tid == 0) {
        const double t = ws_[0] + ws_[1] + ws_[2] + ws_[3];
        const double n = (double)PLANES * IMG_H * IMG_W;
        out[0] = (float)(1.0 - t / n);
    }
}

extern "C" void kernel_launch(void* const* d_in, const int* in_sizes, int n_in,
                              void* d_out, int out_size, void* d_ws, size_t ws_size,
                              hipStream_t stream)
{
    const float* x = (const float*)d_in[0];
    const float* y = (const float*)d_in[1];
    float* out = (float*)d_out;
    float* partials = (float*)d_ws;   // NBLK floats, fully overwritten each call

    dim3 grid(GDX, GDY, PLANES);
    ssim_tile_kernel<<<grid, NT, 0, stream>>>(x, y, partials);
    ssim_finalize_kernel<<<1, NT, 0, stream>>>(partials, out);
}